// Round 1
// baseline (535.950 us; speedup 1.0000x reference)
//
#include <hip/hip_runtime.h>
#include <hip/hip_bf16.h>
#include <math.h>

#define S_LEN 8192
#define DK    128
#define BM    64
#define BN    64
#define NWAVES 4
#define SCALE 0.08838834764831845f   // 1/sqrt(128)

typedef __bf16 bf16x8_t __attribute__((ext_vector_type(8)));
typedef __bf16 bf16x4_t __attribute__((ext_vector_type(4)));
typedef float  floatx4  __attribute__((ext_vector_type(4)));

// Flash attention fwd, causal, fp32 in/out, bf16 MFMA compute.
// Block: 256 threads = 4 waves; each wave owns 16 query rows (BM=64).
// Iterates BN=64-key tiles up to the block's diagonal.
__global__ __launch_bounds__(256, 2)
void fa_fwd(const float* __restrict__ Q, const float* __restrict__ K,
            const float* __restrict__ V, float* __restrict__ O) {
  // K tile row-major bf16 (pad +8 to break power-of-2 strides for frag reads)
  __shared__ __align__(16) __bf16 Ks[BN][DK + 8];        // 64 x 136 = 17.4 KB
  // V tile TRANSPOSED: Vt[d][key] so PV B-frags are 8 contiguous bf16
  __shared__ __align__(16) __bf16 Vt[DK][BN + 8];        // 128 x 72 = 18.4 KB
  // per-wave P round-trip buffer (C-layout -> A-layout)
  __shared__ __align__(16) __bf16 Pl[NWAVES][16][BN + 8]; // 9.2 KB

  const int tid  = threadIdx.x;
  const int wave = tid >> 6;
  const int lane = tid & 63;
  const int l15  = lane & 15;
  const int quad = lane >> 4;

  const int qtile = blockIdx.x;
  const int q0w   = qtile * BM + wave * 16;   // first q row of this wave

  // ---- Q fragments, kept in registers for the whole kernel ----
  // A-layout for 16x16x32: A[m=lane&15][k=quad*8+j]
  bf16x8_t qf[4];
  {
    const float* qrow = Q + (size_t)(q0w + l15) * DK + quad * 8;
    #pragma unroll
    for (int kb = 0; kb < 4; ++kb) {
      const float4* p = (const float4*)(qrow + kb * 32);
      float4 a = p[0], b = p[1];
      bf16x8_t f;
      f[0]=(__bf16)a.x; f[1]=(__bf16)a.y; f[2]=(__bf16)a.z; f[3]=(__bf16)a.w;
      f[4]=(__bf16)b.x; f[5]=(__bf16)b.y; f[6]=(__bf16)b.z; f[7]=(__bf16)b.w;
      qf[kb] = f;
    }
  }

  // ---- online-softmax state ----
  floatx4 o_acc[8];                       // O tile: 8 d-subtiles x 4 rows
  #pragma unroll
  for (int dt = 0; dt < 8; ++dt) o_acc[dt] = (floatx4){0.f, 0.f, 0.f, 0.f};
  float m_r[4], l_r[4];
  #pragma unroll
  for (int r = 0; r < 4; ++r) { m_r[r] = -INFINITY; l_r[r] = 0.f; }

  // staging map: 4 threads per K/V row, 32 cols each
  const int srow = tid >> 2;              // 0..63
  const int scb  = (tid & 3) * 32;        // 0,32,64,96

  for (int jb = 0; jb <= qtile; ++jb) {
    const int key0 = jb * BN;

    // ---- stage K (row-major) and V (transposed) as bf16 ----
    {
      const float* kp = K + (size_t)(key0 + srow) * DK + scb;
      const float* vp = V + (size_t)(key0 + srow) * DK + scb;
      #pragma unroll
      for (int i = 0; i < 8; ++i) {
        float4 kv = ((const float4*)kp)[i];
        bf16x4_t kkv;
        kkv[0]=(__bf16)kv.x; kkv[1]=(__bf16)kv.y; kkv[2]=(__bf16)kv.z; kkv[3]=(__bf16)kv.w;
        *(bf16x4_t*)&Ks[srow][scb + i * 4] = kkv;
        float4 vv = ((const float4*)vp)[i];
        Vt[scb + i * 4 + 0][srow] = (__bf16)vv.x;
        Vt[scb + i * 4 + 1][srow] = (__bf16)vv.y;
        Vt[scb + i * 4 + 2][srow] = (__bf16)vv.z;
        Vt[scb + i * 4 + 3][srow] = (__bf16)vv.w;
      }
    }
    __syncthreads();

    // ---- S = (Q K^T): 4 key sub-tiles of 16, K-dim 128 in 4 chunks ----
    floatx4 sv[4];
    #pragma unroll
    for (int n = 0; n < 4; ++n) {
      floatx4 acc = (floatx4){0.f, 0.f, 0.f, 0.f};
      #pragma unroll
      for (int kb = 0; kb < 4; ++kb) {
        bf16x8_t bfr = *(const bf16x8_t*)&Ks[n * 16 + l15][kb * 32 + quad * 8];
        acc = __builtin_amdgcn_mfma_f32_16x16x32_bf16(qf[kb], bfr, acc, 0, 0, 0);
      }
      sv[n] = acc;
    }

    // ---- scale (+ causal mask only on the diagonal tile) ----
    if (jb == qtile) {
      #pragma unroll
      for (int n = 0; n < 4; ++n) {
        const int key = key0 + n * 16 + l15;
        #pragma unroll
        for (int r = 0; r < 4; ++r) {
          const int qi = q0w + quad * 4 + r;
          float v = sv[n][r] * SCALE;
          sv[n][r] = (key > qi) ? -1e30f : v;
        }
      }
    } else {
      #pragma unroll
      for (int n = 0; n < 4; ++n)
        #pragma unroll
        for (int r = 0; r < 4; ++r) sv[n][r] *= SCALE;
    }

    // ---- online softmax (rows span 16 lanes within each quad) ----
    float rm[4];
    #pragma unroll
    for (int r = 0; r < 4; ++r)
      rm[r] = fmaxf(fmaxf(sv[0][r], sv[1][r]), fmaxf(sv[2][r], sv[3][r]));
    #pragma unroll
    for (int off = 8; off >= 1; off >>= 1) {
      #pragma unroll
      for (int r = 0; r < 4; ++r) rm[r] = fmaxf(rm[r], __shfl_xor(rm[r], off));
    }
    float alpha[4];
    #pragma unroll
    for (int r = 0; r < 4; ++r) {
      const float mn = fmaxf(m_r[r], rm[r]);
      alpha[r] = __expf(m_r[r] - mn);
      m_r[r] = mn;
    }
    float rs[4] = {0.f, 0.f, 0.f, 0.f};
    #pragma unroll
    for (int n = 0; n < 4; ++n) {
      #pragma unroll
      for (int r = 0; r < 4; ++r) {
        const float p = __expf(sv[n][r] - m_r[r]);
        sv[n][r] = p;
        rs[r] += p;
      }
    }
    #pragma unroll
    for (int off = 8; off >= 1; off >>= 1) {
      #pragma unroll
      for (int r = 0; r < 4; ++r) rs[r] += __shfl_xor(rs[r], off);
    }
    #pragma unroll
    for (int r = 0; r < 4; ++r) l_r[r] = l_r[r] * alpha[r] + rs[r];
    #pragma unroll
    for (int dt = 0; dt < 8; ++dt)
      #pragma unroll
      for (int r = 0; r < 4; ++r) o_acc[dt][r] *= alpha[r];

    // ---- P: C-layout -> LDS -> A-layout (per-wave buffer) ----
    #pragma unroll
    for (int n = 0; n < 4; ++n)
      #pragma unroll
      for (int r = 0; r < 4; ++r)
        Pl[wave][quad * 4 + r][n * 16 + l15] = (__bf16)sv[n][r];
    __syncthreads();   // wave-local WAR/RAW ordering + keeps block uniform

    // ---- O += P V ----
    #pragma unroll
    for (int kc = 0; kc < 2; ++kc) {
      bf16x8_t af = *(const bf16x8_t*)&Pl[wave][l15][kc * 32 + quad * 8];
      #pragma unroll
      for (int dt = 0; dt < 8; ++dt) {
        bf16x8_t vf = *(const bf16x8_t*)&Vt[dt * 16 + l15][kc * 32 + quad * 8];
        o_acc[dt] = __builtin_amdgcn_mfma_f32_16x16x32_bf16(af, vf, o_acc[dt], 0, 0, 0);
      }
    }
    __syncthreads();   // all reads of Ks/Vt done before next stage
  }

  // ---- epilogue: normalize and store ----
  #pragma unroll
  for (int r = 0; r < 4; ++r) {
    const float inv = 1.0f / l_r[r];
    float* orow = O + (size_t)(q0w + quad * 4 + r) * DK + l15;
    #pragma unroll
    for (int dt = 0; dt < 8; ++dt) orow[dt * 16] = o_acc[dt][r] * inv;
  }
}

extern "C" void kernel_launch(void* const* d_in, const int* in_sizes, int n_in,
                              void* d_out, int out_size, void* d_ws, size_t ws_size,
                              hipStream_t stream) {
  (void)in_sizes; (void)n_in; (void)out_size; (void)d_ws; (void)ws_size;
  const float* q = (const float*)d_in[0];
  const float* k = (const float*)d_in[1];
  const float* v = (const float*)d_in[2];
  float* out = (float*)d_out;
  fa_fwd<<<S_LEN / BM, 256, 0, stream>>>(q, k, v, out);
}

// Round 2
// 203.441 us; speedup vs baseline: 2.6344x; 2.6344x over previous
//
#include <hip/hip_runtime.h>
#include <hip/hip_bf16.h>
#include <math.h>

#define S_LEN 8192
#define DK    128
#define BM    64
#define BN    64
#define NQT   (S_LEN / BM)     // 128 query tiles
#define NWAVES 4
#define SCALE 0.08838834764831845f   // 1/sqrt(128)

typedef __bf16 bf16x8_t __attribute__((ext_vector_type(8)));
typedef __bf16 bf16x4_t __attribute__((ext_vector_type(4)));
typedef float  floatx4  __attribute__((ext_vector_type(4)));

// Flash attention fwd, causal, fp32 in/out, bf16 MFMA compute.
// Split-K (flash-decoding): block (qtile, g) handles key-tiles
// [g*Ci, min((g+1)*Ci, qtile+1)) with Ci = ceil((qtile+1)/G), writing
// unnormalized partial O + (m,l) stats to ws; fa_reduce combines.
// direct=1 (G==1 fallback): normalize and write O directly.
__global__ __launch_bounds__(256, 2)
void fa_part(const float* __restrict__ Q, const float* __restrict__ K,
             const float* __restrict__ V, float* __restrict__ Opart,
             float* __restrict__ stats, int G, int direct) {
  __shared__ __align__(16) __bf16 Ks[BN][DK + 8];         // 17.4 KB
  __shared__ __align__(16) __bf16 Vt[DK][BN + 8];         // 18.4 KB (V transposed)
  __shared__ __align__(16) __bf16 Pl[NWAVES][16][BN + 8]; // 9.2 KB

  const int tid  = threadIdx.x;
  const int wave = tid >> 6;
  const int lane = tid & 63;
  const int l15  = lane & 15;
  const int quad = lane >> 4;

  const int qtile = blockIdx.x;
  const int g     = blockIdx.y;
  const int nt    = qtile + 1;                  // key tiles before diagonal
  const int Ci    = (nt + G - 1) / G;
  const int jb0   = g * Ci;
  const int jb1   = (jb0 + Ci < nt) ? (jb0 + Ci) : nt;
  const int chunk = qtile * G + g;

  if (jb0 >= jb1) {                             // empty chunk: stats only
    if (tid < BM) {
      stats[((size_t)chunk * BM + tid) * 2 + 0] = -INFINITY;
      stats[((size_t)chunk * BM + tid) * 2 + 1] = 0.f;
    }
    return;
  }

  const int q0w = qtile * BM + wave * 16;       // first q row of this wave

  // ---- Q fragments (A-layout: A[m=lane&15][k=quad*8+j]) ----
  bf16x8_t qf[4];
  {
    const float* qrow = Q + (size_t)(q0w + l15) * DK + quad * 8;
    #pragma unroll
    for (int kb = 0; kb < 4; ++kb) {
      const float4* p = (const float4*)(qrow + kb * 32);
      float4 a = p[0], b = p[1];
      bf16x8_t f;
      f[0]=(__bf16)a.x; f[1]=(__bf16)a.y; f[2]=(__bf16)a.z; f[3]=(__bf16)a.w;
      f[4]=(__bf16)b.x; f[5]=(__bf16)b.y; f[6]=(__bf16)b.z; f[7]=(__bf16)b.w;
      qf[kb] = f;
    }
  }

  floatx4 o_acc[8];
  #pragma unroll
  for (int dt = 0; dt < 8; ++dt) o_acc[dt] = (floatx4){0.f, 0.f, 0.f, 0.f};
  float m_r[4], l_r[4];
  #pragma unroll
  for (int r = 0; r < 4; ++r) { m_r[r] = -INFINITY; l_r[r] = 0.f; }

  const int srow = tid >> 2;                    // staging: 4 thr/row, 32 cols
  const int scb  = (tid & 3) * 32;

  for (int jb = jb0; jb < jb1; ++jb) {
    const int key0 = jb * BN;

    // ---- stage K (row-major bf16) and V (transposed) ----
    {
      const float* kp = K + (size_t)(key0 + srow) * DK + scb;
      const float* vp = V + (size_t)(key0 + srow) * DK + scb;
      #pragma unroll
      for (int i = 0; i < 8; ++i) {
        float4 kv = ((const float4*)kp)[i];
        bf16x4_t kkv;
        kkv[0]=(__bf16)kv.x; kkv[1]=(__bf16)kv.y; kkv[2]=(__bf16)kv.z; kkv[3]=(__bf16)kv.w;
        *(bf16x4_t*)&Ks[srow][scb + i * 4] = kkv;
        float4 vv = ((const float4*)vp)[i];
        Vt[scb + i * 4 + 0][srow] = (__bf16)vv.x;
        Vt[scb + i * 4 + 1][srow] = (__bf16)vv.y;
        Vt[scb + i * 4 + 2][srow] = (__bf16)vv.z;
        Vt[scb + i * 4 + 3][srow] = (__bf16)vv.w;
      }
    }
    __syncthreads();

    // ---- S = Q K^T ----
    floatx4 sv[4];
    #pragma unroll
    for (int n = 0; n < 4; ++n) {
      floatx4 acc = (floatx4){0.f, 0.f, 0.f, 0.f};
      #pragma unroll
      for (int kb = 0; kb < 4; ++kb) {
        bf16x8_t bfr = *(const bf16x8_t*)&Ks[n * 16 + l15][kb * 32 + quad * 8];
        acc = __builtin_amdgcn_mfma_f32_16x16x32_bf16(qf[kb], bfr, acc, 0, 0, 0);
      }
      sv[n] = acc;
    }

    // ---- scale (+ causal mask only on diagonal tile) ----
    if (jb == qtile) {
      #pragma unroll
      for (int n = 0; n < 4; ++n) {
        const int key = key0 + n * 16 + l15;
        #pragma unroll
        for (int r = 0; r < 4; ++r) {
          const int qi = q0w + quad * 4 + r;
          float v = sv[n][r] * SCALE;
          sv[n][r] = (key > qi) ? -1e30f : v;
        }
      }
    } else {
      #pragma unroll
      for (int n = 0; n < 4; ++n)
        #pragma unroll
        for (int r = 0; r < 4; ++r) sv[n][r] *= SCALE;
    }

    // ---- online softmax (rows span 16 lanes within each quad) ----
    float rm[4];
    #pragma unroll
    for (int r = 0; r < 4; ++r)
      rm[r] = fmaxf(fmaxf(sv[0][r], sv[1][r]), fmaxf(sv[2][r], sv[3][r]));
    #pragma unroll
    for (int off = 8; off >= 1; off >>= 1) {
      #pragma unroll
      for (int r = 0; r < 4; ++r) rm[r] = fmaxf(rm[r], __shfl_xor(rm[r], off));
    }
    float alpha[4];
    #pragma unroll
    for (int r = 0; r < 4; ++r) {
      const float mn = fmaxf(m_r[r], rm[r]);
      alpha[r] = __expf(m_r[r] - mn);
      m_r[r] = mn;
    }
    float rs[4] = {0.f, 0.f, 0.f, 0.f};
    #pragma unroll
    for (int n = 0; n < 4; ++n) {
      #pragma unroll
      for (int r = 0; r < 4; ++r) {
        const float p = __expf(sv[n][r] - m_r[r]);
        sv[n][r] = p;
        rs[r] += p;
      }
    }
    #pragma unroll
    for (int off = 8; off >= 1; off >>= 1) {
      #pragma unroll
      for (int r = 0; r < 4; ++r) rs[r] += __shfl_xor(rs[r], off);
    }
    #pragma unroll
    for (int r = 0; r < 4; ++r) l_r[r] = l_r[r] * alpha[r] + rs[r];
    #pragma unroll
    for (int dt = 0; dt < 8; ++dt)
      #pragma unroll
      for (int r = 0; r < 4; ++r) o_acc[dt][r] *= alpha[r];

    // ---- P: C-layout -> LDS -> A-layout ----
    #pragma unroll
    for (int n = 0; n < 4; ++n)
      #pragma unroll
      for (int r = 0; r < 4; ++r)
        Pl[wave][quad * 4 + r][n * 16 + l15] = (__bf16)sv[n][r];
    __syncthreads();

    // ---- O += P V ----
    #pragma unroll
    for (int kc = 0; kc < 2; ++kc) {
      bf16x8_t af = *(const bf16x8_t*)&Pl[wave][l15][kc * 32 + quad * 8];
      #pragma unroll
      for (int dt = 0; dt < 8; ++dt) {
        bf16x8_t vf = *(const bf16x8_t*)&Vt[dt * 16 + l15][kc * 32 + quad * 8];
        o_acc[dt] = __builtin_amdgcn_mfma_f32_16x16x32_bf16(af, vf, o_acc[dt], 0, 0, 0);
      }
    }
    __syncthreads();
  }

  // ---- epilogue ----
  if (direct) {
    #pragma unroll
    for (int r = 0; r < 4; ++r) {
      const float inv = 1.0f / l_r[r];
      float* orow = Opart + (size_t)(q0w + quad * 4 + r) * DK + l15;
      #pragma unroll
      for (int dt = 0; dt < 8; ++dt) orow[dt * 16] = o_acc[dt][r] * inv;
    }
  } else {
    #pragma unroll
    for (int r = 0; r < 4; ++r) {
      const int row = wave * 16 + quad * 4 + r;
      float* orow = Opart + ((size_t)chunk * BM + row) * DK + l15;
      #pragma unroll
      for (int dt = 0; dt < 8; ++dt) orow[dt * 16] = o_acc[dt][r];
    }
    if (l15 == 0) {
      #pragma unroll
      for (int r = 0; r < 4; ++r) {
        const int row = wave * 16 + quad * 4 + r;
        stats[((size_t)chunk * BM + row) * 2 + 0] = m_r[r];
        stats[((size_t)chunk * BM + row) * 2 + 1] = l_r[r];
      }
    }
  }
}

// Combine G partials per query row: O = sum_g w_g*O_g / sum_g w_g*l_g,
// w_g = exp(m_g - M). One block per row, one thread per column.
__global__ void fa_reduce(const float* __restrict__ Opart,
                          const float* __restrict__ stats,
                          float* __restrict__ O, int G) {
  const int row = blockIdx.x;
  const int col = threadIdx.x;
  const int qt  = row >> 6;        // / BM
  const int r   = row & 63;

  float M = -INFINITY;
  for (int g = 0; g < G; ++g)
    M = fmaxf(M, stats[((size_t)(qt * G + g) * BM + r) * 2]);

  float L = 0.f, acc = 0.f;
  for (int g = 0; g < G; ++g) {
    const size_t sidx = (size_t)(qt * G + g) * BM + r;
    const float m = stats[sidx * 2];
    if (m == -INFINITY) continue;
    const float w = __expf(m - M);
    L += stats[sidx * 2 + 1] * w;
    acc += w * Opart[sidx * DK + col];
  }
  O[(size_t)row * DK + col] = acc / L;
}

extern "C" void kernel_launch(void* const* d_in, const int* in_sizes, int n_in,
                              void* d_out, int out_size, void* d_ws, size_t ws_size,
                              hipStream_t stream) {
  (void)in_sizes; (void)n_in; (void)out_size;
  const float* q = (const float*)d_in[0];
  const float* k = (const float*)d_in[1];
  const float* v = (const float*)d_in[2];
  float* out = (float*)d_out;

  // ws per split: NQT tiles x (O-part BM*DK + stats 2*BM) floats = 4.26 MB
  const size_t need_per_g = (size_t)NQT * (BM * DK + 2 * BM) * sizeof(float);
  int G = (int)(ws_size / need_per_g);
  if (G > 8) G = 8;

  if (G >= 2) {
    float* Opart = (float*)d_ws;
    float* stats = Opart + (size_t)NQT * G * BM * DK;
    fa_part<<<dim3(NQT, G), 256, 0, stream>>>(q, k, v, Opart, stats, G, 0);
    fa_reduce<<<S_LEN, DK, 0, stream>>>(Opart, stats, out, G);
  } else {
    // ws too small: direct single-pass (round-1 behavior)
    fa_part<<<dim3(NQT, 1), 256, 0, stream>>>(q, k, v, out, out, 1, 1);
  }
}

// Round 3
// 136.636 us; speedup vs baseline: 3.9225x; 1.4889x over previous
//
#include <hip/hip_runtime.h>
#include <hip/hip_bf16.h>
#include <math.h>

#define S_LEN 8192
#define DK    128
#define BM    64
#define BN    64
#define NQT   (S_LEN / BM)     // 128 query tiles
#define SCALE 0.08838834764831845f   // 1/sqrt(128)

typedef __bf16 bf16x8_t __attribute__((ext_vector_type(8)));
typedef __bf16 bf16x4_t __attribute__((ext_vector_type(4)));
typedef float  floatx4  __attribute__((ext_vector_type(4)));

// async global->LDS, 16 B per lane; LDS dst is wave-uniform base + lane*16
#define GLD16(g, l) __builtin_amdgcn_global_load_lds(                      \
    (const __attribute__((address_space(1))) void*)(g),                    \
    (__attribute__((address_space(3))) void*)(l), 16, 0, 0)

// ---- prep: K fp32 -> bf16 row-major (one-time) ----
__global__ __launch_bounds__(256) void prep_k(const float* __restrict__ K,
                                              __bf16* __restrict__ Kb) {
  const int i = (blockIdx.x * 256 + threadIdx.x) * 4;
  float4 v = *(const float4*)&K[i];
  bf16x4_t b;
  b[0] = (__bf16)v.x; b[1] = (__bf16)v.y; b[2] = (__bf16)v.z; b[3] = (__bf16)v.w;
  *(bf16x4_t*)&Kb[i] = b;
}

// ---- prep: V fp32 -> bf16 TRANSPOSED global Vt[d][s] (one-time) ----
__global__ __launch_bounds__(256) void prep_vt(const float* __restrict__ V,
                                               __bf16* __restrict__ Vt) {
  __shared__ __bf16 t[64][DK + 8];
  const int tid  = threadIdx.x;
  const int key0 = blockIdx.x * 64;
  {
    const int r = tid >> 2, cg = (tid & 3) * 32;
    const float* vp = V + (size_t)(key0 + r) * DK + cg;
    #pragma unroll
    for (int i = 0; i < 8; ++i) {
      float4 v = ((const float4*)vp)[i];
      bf16x4_t b;
      b[0] = (__bf16)v.x; b[1] = (__bf16)v.y; b[2] = (__bf16)v.z; b[3] = (__bf16)v.w;
      *(bf16x4_t*)&t[r][cg + i * 4] = b;
    }
  }
  __syncthreads();
  const int d = tid >> 1, h = (tid & 1) * 32;
  __bf16* op = Vt + (size_t)d * S_LEN + key0 + h;
  #pragma unroll
  for (int jb = 0; jb < 4; ++jb) {
    bf16x8_t b;
    #pragma unroll
    for (int j = 0; j < 8; ++j) b[j] = t[h + jb * 8 + j][d];
    *(bf16x8_t*)&op[jb * 8] = b;
  }
}

// ---- flash attention partial, split-K over key chunks ----
// Ks: 64 key-rows x 128 d, bf16, XOR-swizzled 16B chunks: phys = c ^ (row&15)
// Vts: 128 d-rows x 64 keys, bf16, swizzled: phys = c ^ (row&7)
__global__ __launch_bounds__(256, 3)
void fa_part(const float* __restrict__ Q, const __bf16* __restrict__ Kb,
             const __bf16* __restrict__ Vtg, float* __restrict__ Opart,
             float* __restrict__ stats, int G, int direct) {
  __shared__ __align__(16) __bf16 Ks[BN * DK];        // 16 KB
  __shared__ __align__(16) __bf16 Vts[DK * BN];       // 16 KB
  __shared__ __align__(16) __bf16 Pl[4][16][BN + 8];  // 9.2 KB

  const int tid  = threadIdx.x;
  const int wave = tid >> 6;
  const int lane = tid & 63;
  const int l15  = lane & 15;
  const int quad = lane >> 4;

  const int qtile = blockIdx.x;
  const int g     = blockIdx.y;
  const int nt    = qtile + 1;
  const int Ci    = (nt + G - 1) / G;
  const int jb0   = g * Ci;
  const int jb1   = (jb0 + Ci < nt) ? (jb0 + Ci) : nt;
  const int chunk = qtile * G + g;

  if (jb0 >= jb1) {
    if (tid < BM) {
      stats[((size_t)chunk * BM + tid) * 2 + 0] = -INFINITY;
      stats[((size_t)chunk * BM + tid) * 2 + 1] = 0.f;
    }
    return;
  }

  const int q0w = qtile * BM + wave * 16;

  // Q fragments (A-layout), fp32 global -> bf16 regs, once per block
  bf16x8_t qf[4];
  {
    const float* qrow = Q + (size_t)(q0w + l15) * DK + quad * 8;
    #pragma unroll
    for (int kb = 0; kb < 4; ++kb) {
      const float4* p = (const float4*)(qrow + kb * 32);
      float4 a = p[0], b = p[1];
      bf16x8_t f;
      f[0]=(__bf16)a.x; f[1]=(__bf16)a.y; f[2]=(__bf16)a.z; f[3]=(__bf16)a.w;
      f[4]=(__bf16)b.x; f[5]=(__bf16)b.y; f[6]=(__bf16)b.z; f[7]=(__bf16)b.w;
      qf[kb] = f;
    }
  }

  // per-thread staging sources (swizzled) + wave-uniform LDS dsts
  const __bf16* kp[4]; const __bf16* vp[4];
  __bf16* kl[4]; __bf16* vl[4];
  {
    const int ck = l15 ^ ((wave * 4 + (lane >> 4)) & 15);
    const int cv = (lane & 7) ^ ((lane >> 3) & 7);
    #pragma unroll
    for (int t = 0; t < 4; ++t) {
      const int rk = t * 16 + wave * 4 + (lane >> 4);
      kp[t] = Kb + ((size_t)(jb0 * BN + rk)) * DK + ck * 8;
      kl[t] = &Ks[t * 2048 + wave * 512];
      const int rv = t * 32 + wave * 8 + (lane >> 3);
      vp[t] = Vtg + (size_t)rv * S_LEN + jb0 * BN + cv * 8;
      vl[t] = &Vts[t * 2048 + wave * 512];
    }
  }

  floatx4 o_acc[8];
  #pragma unroll
  for (int dt = 0; dt < 8; ++dt) o_acc[dt] = (floatx4){0.f, 0.f, 0.f, 0.f};
  float m_r[4], l_r[4];
  #pragma unroll
  for (int r = 0; r < 4; ++r) { m_r[r] = -INFINITY; l_r[r] = 0.f; }

  for (int jb = jb0; jb < jb1; ++jb) {
    const int key0 = jb * BN;

    // ---- async stage K-tile + Vt-tile (bf16, pre-converted) ----
    #pragma unroll
    for (int t = 0; t < 4; ++t) {
      GLD16(kp[t], kl[t]);
      GLD16(vp[t], vl[t]);
      kp[t] += BN * DK;
      vp[t] += BN;
    }
    __syncthreads();

    // ---- S = Q K^T (swizzled B-frag reads) ----
    floatx4 sv[4];
    #pragma unroll
    for (int n = 0; n < 4; ++n) {
      floatx4 acc = (floatx4){0.f, 0.f, 0.f, 0.f};
      #pragma unroll
      for (int kb = 0; kb < 4; ++kb) {
        bf16x8_t bfr = *(const bf16x8_t*)
            &Ks[(n * 16 + l15) * DK + (((kb * 4 + quad) ^ l15) * 8)];
        acc = __builtin_amdgcn_mfma_f32_16x16x32_bf16(qf[kb], bfr, acc, 0, 0, 0);
      }
      sv[n] = acc;
    }

    // ---- scale (+ causal mask on diagonal tile only) ----
    if (jb == qtile) {
      #pragma unroll
      for (int n = 0; n < 4; ++n) {
        const int key = key0 + n * 16 + l15;
        #pragma unroll
        for (int r = 0; r < 4; ++r) {
          const int qi = q0w + quad * 4 + r;
          float v = sv[n][r] * SCALE;
          sv[n][r] = (key > qi) ? -1e30f : v;
        }
      }
    } else {
      #pragma unroll
      for (int n = 0; n < 4; ++n)
        #pragma unroll
        for (int r = 0; r < 4; ++r) sv[n][r] *= SCALE;
    }

    // ---- online softmax ----
    float rm[4];
    #pragma unroll
    for (int r = 0; r < 4; ++r)
      rm[r] = fmaxf(fmaxf(sv[0][r], sv[1][r]), fmaxf(sv[2][r], sv[3][r]));
    #pragma unroll
    for (int off = 8; off >= 1; off >>= 1) {
      #pragma unroll
      for (int r = 0; r < 4; ++r) rm[r] = fmaxf(rm[r], __shfl_xor(rm[r], off));
    }
    float alpha[4];
    #pragma unroll
    for (int r = 0; r < 4; ++r) {
      const float mn = fmaxf(m_r[r], rm[r]);
      alpha[r] = __expf(m_r[r] - mn);
      m_r[r] = mn;
    }
    float rs[4] = {0.f, 0.f, 0.f, 0.f};
    #pragma unroll
    for (int n = 0; n < 4; ++n) {
      #pragma unroll
      for (int r = 0; r < 4; ++r) {
        const float p = __expf(sv[n][r] - m_r[r]);
        sv[n][r] = p;
        rs[r] += p;
      }
    }
    #pragma unroll
    for (int off = 8; off >= 1; off >>= 1) {
      #pragma unroll
      for (int r = 0; r < 4; ++r) rs[r] += __shfl_xor(rs[r], off);
    }
    #pragma unroll
    for (int r = 0; r < 4; ++r) l_r[r] = l_r[r] * alpha[r] + rs[r];
    #pragma unroll
    for (int dt = 0; dt < 8; ++dt)
      #pragma unroll
      for (int r = 0; r < 4; ++r) o_acc[dt][r] *= alpha[r];

    // ---- P: C-layout -> LDS -> A-layout ----
    #pragma unroll
    for (int n = 0; n < 4; ++n)
      #pragma unroll
      for (int r = 0; r < 4; ++r)
        Pl[wave][quad * 4 + r][n * 16 + l15] = (__bf16)sv[n][r];
    __syncthreads();

    // ---- O += P V (swizzled V-frag reads) ----
    #pragma unroll
    for (int kc = 0; kc < 2; ++kc) {
      bf16x8_t af = *(const bf16x8_t*)&Pl[wave][l15][kc * 32 + quad * 8];
      #pragma unroll
      for (int dt = 0; dt < 8; ++dt) {
        bf16x8_t vf = *(const bf16x8_t*)
            &Vts[(dt * 16 + l15) * BN + (((kc * 4 + quad) ^ (l15 & 7)) * 8)];
        o_acc[dt] = __builtin_amdgcn_mfma_f32_16x16x32_bf16(af, vf, o_acc[dt], 0, 0, 0);
      }
    }
    __syncthreads();
  }

  // ---- epilogue ----
  if (direct) {
    #pragma unroll
    for (int r = 0; r < 4; ++r) {
      const float inv = 1.0f / l_r[r];
      float* orow = Opart + (size_t)(q0w + quad * 4 + r) * DK + l15;
      #pragma unroll
      for (int dt = 0; dt < 8; ++dt) orow[dt * 16] = o_acc[dt][r] * inv;
    }
  } else {
    #pragma unroll
    for (int r = 0; r < 4; ++r) {
      const int row = wave * 16 + quad * 4 + r;
      float* orow = Opart + ((size_t)chunk * BM + row) * DK + l15;
      #pragma unroll
      for (int dt = 0; dt < 8; ++dt) orow[dt * 16] = o_acc[dt][r];
    }
    if (l15 == 0) {
      #pragma unroll
      for (int r = 0; r < 4; ++r) {
        const int row = wave * 16 + quad * 4 + r;
        stats[((size_t)chunk * BM + row) * 2 + 0] = m_r[r];
        stats[((size_t)chunk * BM + row) * 2 + 1] = l_r[r];
      }
    }
  }
}

// ---- combine: wave per query row, lane covers a float2 column pair ----
__global__ __launch_bounds__(256)
void fa_reduce(const float* __restrict__ Opart, const float* __restrict__ stats,
               float* __restrict__ O, int G) {
  const int wave = threadIdx.x >> 6, lane = threadIdx.x & 63;
  const int row = blockIdx.x * 4 + wave;
  const int qt = row >> 6, r = row & 63;

  float M = -INFINITY;
  for (int g = 0; g < G; ++g)
    M = fmaxf(M, stats[((size_t)(qt * G + g) * BM + r) * 2]);

  float L = 0.f;
  float ax = 0.f, ay = 0.f;
  for (int g = 0; g < G; ++g) {
    const size_t sidx = (size_t)(qt * G + g) * BM + r;
    const float m = stats[sidx * 2];
    if (m == -INFINITY) continue;
    const float w = __expf(m - M);
    L += stats[sidx * 2 + 1] * w;
    float2 o = *(const float2*)&Opart[sidx * DK + lane * 2];
    ax += w * o.x; ay += w * o.y;
  }
  const float inv = 1.f / L;
  float2 res; res.x = ax * inv; res.y = ay * inv;
  *(float2*)&O[(size_t)row * DK + lane * 2] = res;
}

extern "C" void kernel_launch(void* const* d_in, const int* in_sizes, int n_in,
                              void* d_out, int out_size, void* d_ws, size_t ws_size,
                              hipStream_t stream) {
  (void)in_sizes; (void)n_in; (void)out_size;
  const float* q = (const float*)d_in[0];
  const float* k = (const float*)d_in[1];
  const float* v = (const float*)d_in[2];
  float* out = (float*)d_out;

  const size_t conv_bytes = (size_t)S_LEN * DK * 2 * 2;          // Kb + Vt = 4 MB
  const size_t per_g = (size_t)NQT * (BM * DK + 2 * BM) * 4;     // 4.26 MB
  int G = 1;
  if (ws_size > conv_bytes + per_g) {
    G = (int)((ws_size - conv_bytes) / per_g);
    if (G > 8) G = 8;
  }

  __bf16* Kb = (__bf16*)d_ws;
  __bf16* Vt = Kb + (size_t)S_LEN * DK;
  float* Opart = (float*)(Vt + (size_t)S_LEN * DK);
  float* stats = Opart + (size_t)NQT * G * BM * DK;

  prep_k<<<(S_LEN * DK) / (256 * 4), 256, 0, stream>>>(k, Kb);
  prep_vt<<<S_LEN / 64, 256, 0, stream>>>(v, Vt);

  if (G >= 2) {
    fa_part<<<dim3(NQT, G), 256, 0, stream>>>(q, Kb, Vt, Opart, stats, G, 0);
    fa_reduce<<<S_LEN / 4, 256, 0, stream>>>(Opart, stats, out, G);
  } else {
    fa_part<<<dim3(NQT, 1), 256, 0, stream>>>(q, Kb, Vt, out, out, 1, 1);
  }
}